// Round 4
// baseline (257.326 us; speedup 1.0000x reference)
//
#include <hip/hip_runtime.h>
#include <hip/hip_bf16.h>
#include <stdint.h>

typedef __bf16 bf16_t;
typedef __bf16 bf16x4 __attribute__((ext_vector_type(4)));
typedef __bf16 bf16x8 __attribute__((ext_vector_type(8)));
typedef float  f32x4  __attribute__((ext_vector_type(4)));

#define MFMA16(a,b,c) __builtin_amdgcn_mfma_f32_16x16x32_bf16((a),(b),(c),0,0,0)

static constexpr int DIM = 1024, HEADS = 16, HD = 64, NB = 2, NQ = 2048, NKK = 2048;
static constexpr int MROWS = NB * NQ; // 4096 token rows

// ---------------- f32 -> bf16 convert (vectorized) ----------------
__global__ void cvt_f32_bf16(const float* __restrict__ in, bf16_t* __restrict__ out, int n4) {
  int i = blockIdx.x * 256 + threadIdx.x;
  if (i >= n4) return;
  float4 v = reinterpret_cast<const float4*>(in)[i];
  bf16x4 o;
  o[0] = (bf16_t)v.x; o[1] = (bf16_t)v.y; o[2] = (bf16_t)v.z; o[3] = (bf16_t)v.w;
  *reinterpret_cast<bf16x4*>(out + (size_t)i * 4) = o;
}

// ---------------- LDS staging with chunk-XOR swizzle ----------------
// Tile: ROWS x 64 bf16 (128B/row = 8 x 16B chunks). LDS linear; global SOURCE
// pre-swizzled (chunk x fetches global chunk x^(r&7)); reads un-swizzle.
template<int ROWS>
__device__ __forceinline__ void stage_swz(const bf16_t* gbase, int gstride, bf16_t* lds, int tid) {
#pragma unroll
  for (int c = 0; c < ROWS / 32; ++c) {          // 256 chunks per iteration
    int p = c * 256 + tid;                        // 16B-chunk index
    int r = p >> 3, x = p & 7;
    const bf16_t* src = gbase + (size_t)r * gstride + ((x ^ (r & 7)) << 3);
    __builtin_amdgcn_global_load_lds(
        (const __attribute__((address_space(1))) void*)src,
        (__attribute__((address_space(3))) void*)(lds + (p << 3)),
        16, 0, 0);
  }
}

__device__ __forceinline__ bf16x8 lds_read8_swz(const bf16_t* lds, int row, int chunk) {
  int sc = chunk ^ (row & 7);
  return *reinterpret_cast<const bf16x8*>(lds + row * 64 + (sc << 3));
}

// ---------------- GEMM: C[M,N] = A(MxK) * Bt(NxK)^T ----------------
// MODE 0: bf16 row-major out (scaled). MODE 1: f32 row-major + bias.
// MODE 2: bf16 out scattered to per-head-transposed V layout (B,H,Dh,NK).
template<int MODE>
__global__ __launch_bounds__(256) void gemm_bt(const bf16_t* __restrict__ A,
                                               const bf16_t* __restrict__ Bt,
                                               void* __restrict__ Cout,
                                               const float* __restrict__ bias,
                                               int M, int N, int K, float scale) {
  __shared__ __align__(16) bf16_t As[128 * 64];
  __shared__ __align__(16) bf16_t Bs[128 * 64];
  const int tid = threadIdx.x;
  const int lane = tid & 63, wid = tid >> 6;
  const int l15 = lane & 15, lg = lane >> 4;
  const int wr = wid >> 1, wc = wid & 1;       // wave 64x64 sub-tile
  const int bn = blockIdx.x, bm = blockIdx.y;

  const bf16_t* Abase = A + (size_t)(bm * 128) * K;
  const bf16_t* Bbase = Bt + (size_t)(bn * 128) * K;

  f32x4 acc[4][4];
#pragma unroll
  for (int m = 0; m < 4; ++m)
#pragma unroll
    for (int n = 0; n < 4; ++n) acc[m][n] = (f32x4){0.f, 0.f, 0.f, 0.f};

  for (int k0 = 0; k0 < K; k0 += 64) {
    __syncthreads();
    stage_swz<128>(Abase + k0, K, As, tid);
    stage_swz<128>(Bbase + k0, K, Bs, tid);
    __syncthreads();
#pragma unroll
    for (int kk = 0; kk < 2; ++kk) {
      bf16x8 af[4], bfr[4];
#pragma unroll
      for (int m = 0; m < 4; ++m) af[m] = lds_read8_swz(As, wr * 64 + m * 16 + l15, kk * 4 + lg);
#pragma unroll
      for (int n = 0; n < 4; ++n) bfr[n] = lds_read8_swz(Bs, wc * 64 + n * 16 + l15, kk * 4 + lg);
#pragma unroll
      for (int m = 0; m < 4; ++m)
#pragma unroll
        for (int n = 0; n < 4; ++n)
          acc[m][n] = MFMA16(af[m], bfr[n], acc[m][n]);
    }
  }

  if (MODE == 2) {
    // V^T per head: Vt[((b*16+h)*64+d)*2048 + kv]; pack 4 consecutive kv (j).
#pragma unroll
    for (int m = 0; m < 4; ++m) {
      int row0 = bm * 128 + wr * 64 + m * 16 + lg * 4;
      int bb = row0 >> 11, kv = row0 & 2047;
#pragma unroll
      for (int n = 0; n < 4; ++n) {
        int col = bn * 128 + wc * 64 + n * 16 + l15;
        int hh = col >> 6, dd = col & 63;
        bf16x4 pk;
#pragma unroll
        for (int j = 0; j < 4; ++j) pk[j] = (bf16_t)acc[m][n][j];
        *reinterpret_cast<bf16x4*>(((bf16_t*)Cout) + (((size_t)((bb * 16 + hh) * 64 + dd)) << 11) + kv) = pk;
      }
    }
  } else {
#pragma unroll
    for (int m = 0; m < 4; ++m)
#pragma unroll
      for (int n = 0; n < 4; ++n)
#pragma unroll
        for (int j = 0; j < 4; ++j) {
          int row = bm * 128 + wr * 64 + m * 16 + lg * 4 + j;
          int col = bn * 128 + wc * 64 + n * 16 + l15;
          float v = acc[m][n][j];
          if (MODE == 0) ((bf16_t*)Cout)[(size_t)row * N + col] = (bf16_t)(v * scale);
          else           ((float*)Cout)[(size_t)row * N + col] = v + bias[col];
        }
  }
}

// ---------------- fused flash attention (R0-proven 16x16 semantics) --------
// grid (NQ/64, HEADS, B) XCD-swizzled; 4 waves x 16 q-rows. V pre-transposed
// (B,H,Dh,NK). Structural upgrades vs R0: double-buffered K/V with
// issue-early staging (1 barrier/iter), P-pad 72 (4-way store conflicts, was
// 8-way at pad 80), exp2-domain softmax (scale folded into Q projection),
// setprio around MFMA clusters.
__global__ __launch_bounds__(256) void attn_fused(const bf16_t* __restrict__ Qp,
                                                  const bf16_t* __restrict__ Kp,
                                                  const bf16_t* __restrict__ Vt,
                                                  bf16_t* __restrict__ Xa) {
  __shared__ __align__(16) bf16_t Ks[2][64 * 64];
  __shared__ __align__(16) bf16_t Vs[2][64 * 64];
  __shared__ __align__(16) bf16_t Ps[4][16 * 72];   // pad 72: rows 16B-aligned, 4-way stores
  const int tid = threadIdx.x;
  const int lane = tid & 63, wid = tid >> 6;
  const int l15 = lane & 15, lg = lane >> 4;

  // bijective XCD swizzle over 1024 workgroups: XCD k hosts 4 heads x 1 batch
  int id = blockIdx.x + 32 * (blockIdx.y + 16 * blockIdx.z);
  int swz = (id & 7) * 128 + (id >> 3);
  const int bx = swz & 31, h = (swz >> 5) & 15, b = swz >> 9;
  const int q0 = bx * 64;

  const bf16_t* qbase = Qp + ((size_t)(b * NQ + q0)) * DIM + h * HD;
  const bf16_t* kbase = Kp + ((size_t)b * NKK) * DIM + h * HD;
  const bf16_t* vbase = Vt + ((size_t)((b * HEADS + h) * HD)) * NKK;

  // ---- stage Q (64x64, reusing Ks[0]) and hoist per-wave fragments ----
  stage_swz<64>(qbase, DIM, &Ks[0][0], tid);
  __syncthreads();
  bf16x8 qf[2];
  qf[0] = lds_read8_swz(&Ks[0][0], wid * 16 + l15, lg);
  qf[1] = lds_read8_swz(&Ks[0][0], wid * 16 + l15, 4 + lg);
  __syncthreads();   // qf reads drained before K restage

  float m_[4] = {-1e30f, -1e30f, -1e30f, -1e30f};
  float l_[4] = {0.f, 0.f, 0.f, 0.f};
  f32x4 o[4];
#pragma unroll
  for (int n = 0; n < 4; ++n) o[n] = (f32x4){0.f, 0.f, 0.f, 0.f};

  // prologue: stage tile 0
  stage_swz<64>(kbase, DIM, &Ks[0][0], tid);
  stage_swz<64>(vbase, NKK, &Vs[0][0], tid);
  __syncthreads();

  int cur = 0;
  for (int it = 0; it < NKK / 64; ++it) {
    // issue next tile early; HBM latency hides under QK^T/softmax/PV
    if (it + 1 < NKK / 64) {
      stage_swz<64>(kbase + (size_t)(it + 1) * 64 * DIM, DIM, &Ks[cur ^ 1][0], tid);
      stage_swz<64>(vbase + (it + 1) * 64, NKK, &Vs[cur ^ 1][0], tid);
    }
    const bf16_t* kl = &Ks[cur][0];
    const bf16_t* vl = &Vs[cur][0];

    // ---- S = Q K^T (exp2-domain scale pre-folded into Q projection) ----
    f32x4 s[4];
#pragma unroll
    for (int t = 0; t < 4; ++t) s[t] = (f32x4){0.f, 0.f, 0.f, 0.f};
    __builtin_amdgcn_s_setprio(1);
#pragma unroll
    for (int t = 0; t < 4; ++t) {
      bf16x8 kf0 = lds_read8_swz(kl, t * 16 + l15, lg);
      bf16x8 kf1 = lds_read8_swz(kl, t * 16 + l15, 4 + lg);
      s[t] = MFMA16(qf[0], kf0, s[t]);
      s[t] = MFMA16(qf[1], kf1, s[t]);
    }
    __builtin_amdgcn_s_setprio(0);

    // ---- online softmax (row = q, spread over 16 lanes l15 x 4 subtiles) ----
    float mn[4], alpha[4], rs[4];
#pragma unroll
    for (int j = 0; j < 4; ++j) {
      float rm = fmaxf(fmaxf(s[0][j], s[1][j]), fmaxf(s[2][j], s[3][j]));
      rm = fmaxf(rm, __shfl_xor(rm, 1));
      rm = fmaxf(rm, __shfl_xor(rm, 2));
      rm = fmaxf(rm, __shfl_xor(rm, 4));
      rm = fmaxf(rm, __shfl_xor(rm, 8));
      mn[j] = fmaxf(m_[j], rm);
      alpha[j] = exp2f(m_[j] - mn[j]);
      m_[j] = mn[j];
      rs[j] = 0.f;
    }
#pragma unroll
    for (int t = 0; t < 4; ++t)
#pragma unroll
      for (int j = 0; j < 4; ++j) {
        float p = exp2f(s[t][j] - mn[j]);
        s[t][j] = p;
        rs[j] += p;
      }
#pragma unroll
    for (int j = 0; j < 4; ++j) {
      rs[j] += __shfl_xor(rs[j], 1);
      rs[j] += __shfl_xor(rs[j], 2);
      rs[j] += __shfl_xor(rs[j], 4);
      rs[j] += __shfl_xor(rs[j], 8);
      l_[j] = l_[j] * alpha[j] + rs[j];
    }
#pragma unroll
    for (int n = 0; n < 4; ++n)
#pragma unroll
      for (int j = 0; j < 4; ++j) o[n][j] *= alpha[j];

    // ---- P -> LDS (D-layout) then re-read as A-operand layout ----
    bf16_t* Pw = &Ps[wid][0];
#pragma unroll
    for (int t = 0; t < 4; ++t)
#pragma unroll
      for (int j = 0; j < 4; ++j)
        Pw[(lg * 4 + j) * 72 + t * 16 + l15] = (bf16_t)s[t][j];
    asm volatile("s_waitcnt lgkmcnt(0)" ::: "memory");
    bf16x8 pf0 = *reinterpret_cast<const bf16x8*>(Pw + l15 * 72 + lg * 8);
    bf16x8 pf1 = *reinterpret_cast<const bf16x8*>(Pw + l15 * 72 + 32 + lg * 8);

    // ---- O += P * V   (B-operand rows = d in Vs[d][kv]) ----
    __builtin_amdgcn_s_setprio(1);
#pragma unroll
    for (int n = 0; n < 4; ++n) {
      bf16x8 vf0 = lds_read8_swz(vl, n * 16 + l15, lg);
      bf16x8 vf1 = lds_read8_swz(vl, n * 16 + l15, 4 + lg);
      o[n] = MFMA16(pf0, vf0, o[n]);
      o[n] = MFMA16(pf1, vf1, o[n]);
    }
    __builtin_amdgcn_s_setprio(0);

    __syncthreads();   // drains vmcnt(0): next tile staged; everyone done with cur
    cur ^= 1;
  }

  // epilogue: normalize and store bf16
#pragma unroll
  for (int j = 0; j < 4; ++j) {
    float inv = 1.f / l_[j];
    int q = q0 + wid * 16 + lg * 4 + j;
#pragma unroll
    for (int n = 0; n < 4; ++n) {
      int d = h * HD + n * 16 + l15;
      Xa[((size_t)(b * NQ + q)) * DIM + d] = (bf16_t)(o[n][j] * inv);
    }
  }
}

// ---------------- launcher ----------------
extern "C" void kernel_launch(void* const* d_in, const int* in_sizes, int n_in,
                              void* d_out, int out_size, void* d_ws, size_t ws_size,
                              hipStream_t stream) {
  (void)in_sizes; (void)n_in; (void)out_size; (void)ws_size;
  const float* q  = (const float*)d_in[0];
  const float* k  = (const float*)d_in[1];
  const float* v  = (const float*)d_in[2];
  const float* Wq = (const float*)d_in[5];
  const float* Wk = (const float*)d_in[6];
  const float* Wv = (const float*)d_in[7];
  const float* Wo = (const float*)d_in[8];
  const float* bo = (const float*)d_in[9];
  float* out = (float*)d_out;

  bf16_t* ws = (bf16_t*)d_ws;
  const size_t SZ_IN = (size_t)MROWS * DIM;  // 4M elems
  const size_t SZ_W  = (size_t)DIM * DIM;    // 1M elems
  bf16_t* qb  = ws;
  bf16_t* kb  = qb  + SZ_IN;
  bf16_t* vb  = kb  + SZ_IN;
  bf16_t* wqb = vb  + SZ_IN;
  bf16_t* wkb = wqb + SZ_W;
  bf16_t* wvb = wkb + SZ_W;
  bf16_t* wob = wvb + SZ_W;
  bf16_t* Qp  = wob + SZ_W;
  bf16_t* Kp  = Qp  + SZ_IN;
  bf16_t* Vtp = Kp  + SZ_IN;
  bf16_t* Xa  = qb;  // alias: qb dead after Q projection (stream-ordered)

  cvt_f32_bf16<<<dim3((unsigned)(SZ_IN / 1024)), 256, 0, stream>>>(q, qb, (int)(SZ_IN / 4));
  cvt_f32_bf16<<<dim3((unsigned)(SZ_IN / 1024)), 256, 0, stream>>>(k, kb, (int)(SZ_IN / 4));
  cvt_f32_bf16<<<dim3((unsigned)(SZ_IN / 1024)), 256, 0, stream>>>(v, vb, (int)(SZ_IN / 4));
  cvt_f32_bf16<<<dim3((unsigned)(SZ_W / 1024)), 256, 0, stream>>>(Wq, wqb, (int)(SZ_W / 4));
  cvt_f32_bf16<<<dim3((unsigned)(SZ_W / 1024)), 256, 0, stream>>>(Wk, wkb, (int)(SZ_W / 4));
  cvt_f32_bf16<<<dim3((unsigned)(SZ_W / 1024)), 256, 0, stream>>>(Wv, wvb, (int)(SZ_W / 4));
  cvt_f32_bf16<<<dim3((unsigned)(SZ_W / 1024)), 256, 0, stream>>>(Wo, wob, (int)(SZ_W / 4));

  dim3 gg(DIM / 128, MROWS / 128);  // (8, 32)
  // Q projection pre-scaled by 0.125 * log2(e) for the exp2-domain softmax
  gemm_bt<0><<<gg, 256, 0, stream>>>(qb, wqb, (void*)Qp, nullptr, MROWS, DIM, DIM, 0.18033688011112042f);
  gemm_bt<0><<<gg, 256, 0, stream>>>(kb, wkb, (void*)Kp, nullptr, MROWS, DIM, DIM, 1.0f);
  gemm_bt<2><<<gg, 256, 0, stream>>>(vb, wvb, (void*)Vtp, nullptr, MROWS, DIM, DIM, 1.0f);

  attn_fused<<<dim3(NQ / 64, HEADS, NB), 256, 0, stream>>>(Qp, Kp, Vtp, Xa);

  gemm_bt<1><<<gg, 256, 0, stream>>>(Xa, wob, (void*)out, bo, MROWS, DIM, DIM, 1.0f);
}

// Round 5
// 204.837 us; speedup vs baseline: 1.2562x; 1.2562x over previous
//
#include <hip/hip_runtime.h>
#include <hip/hip_bf16.h>
#include <stdint.h>

typedef __bf16 bf16_t;
typedef __bf16 bf16x4 __attribute__((ext_vector_type(4)));
typedef __bf16 bf16x8 __attribute__((ext_vector_type(8)));
typedef float  f32x4  __attribute__((ext_vector_type(4)));
typedef unsigned u32x2 __attribute__((ext_vector_type(2)));

#define MFMA16(a,b,c) __builtin_amdgcn_mfma_f32_16x16x32_bf16((a),(b),(c),0,0,0)

static constexpr int DIM = 1024, HEADS = 16, HD = 64, NB = 2, NQ = 2048, NKK = 2048;
static constexpr int MROWS = NB * NQ; // 4096 token rows

// ---------------- f32 -> bf16 convert (vectorized) ----------------
__global__ void cvt_f32_bf16(const float* __restrict__ in, bf16_t* __restrict__ out, int n4) {
  int i = blockIdx.x * 256 + threadIdx.x;
  if (i >= n4) return;
  float4 v = reinterpret_cast<const float4*>(in)[i];
  bf16x4 o;
  o[0] = (bf16_t)v.x; o[1] = (bf16_t)v.y; o[2] = (bf16_t)v.z; o[3] = (bf16_t)v.w;
  *reinterpret_cast<bf16x4*>(out + (size_t)i * 4) = o;
}

// ---------------- LDS staging with chunk-XOR swizzle ----------------
template<int ROWS>
__device__ __forceinline__ void stage_swz(const bf16_t* gbase, int gstride, bf16_t* lds, int tid) {
#pragma unroll
  for (int c = 0; c < ROWS / 32; ++c) {          // 256 chunks per iteration
    int p = c * 256 + tid;                        // 16B-chunk index
    int r = p >> 3, x = p & 7;
    const bf16_t* src = gbase + (size_t)r * gstride + ((x ^ (r & 7)) << 3);
    __builtin_amdgcn_global_load_lds(
        (const __attribute__((address_space(1))) void*)src,
        (__attribute__((address_space(3))) void*)(lds + (p << 3)),
        16, 0, 0);
  }
}

__device__ __forceinline__ bf16x8 lds_read8_swz(const bf16_t* lds, int row, int chunk) {
  int sc = chunk ^ (row & 7);
  return *reinterpret_cast<const bf16x8*>(lds + row * 64 + (sc << 3));
}

__device__ __forceinline__ unsigned cvtpk_bf16(float lo, float hi) {
  unsigned r;
  asm("v_cvt_pk_bf16_f32 %0, %1, %2" : "=v"(r) : "v"(lo), "v"(hi));
  return r;
}

// ---------------- GEMM: C[M,N] = A(MxK) * Bt(NxK)^T ----------------
// MODE 0: bf16 row-major out (scaled). MODE 1: f32 row-major + bias.
// MODE 2: bf16 out scattered to per-head-transposed V layout (B,H,Dh,NK).
template<int MODE>
__global__ __launch_bounds__(256) void gemm_bt(const bf16_t* __restrict__ A,
                                               const bf16_t* __restrict__ Bt,
                                               void* __restrict__ Cout,
                                               const float* __restrict__ bias,
                                               int M, int N, int K, float scale) {
  __shared__ __align__(16) bf16_t As[128 * 64];
  __shared__ __align__(16) bf16_t Bs[128 * 64];
  const int tid = threadIdx.x;
  const int lane = tid & 63, wid = tid >> 6;
  const int l15 = lane & 15, lg = lane >> 4;
  const int wr = wid >> 1, wc = wid & 1;       // wave 64x64 sub-tile
  const int bn = blockIdx.x, bm = blockIdx.y;

  const bf16_t* Abase = A + (size_t)(bm * 128) * K;
  const bf16_t* Bbase = Bt + (size_t)(bn * 128) * K;

  f32x4 acc[4][4];
#pragma unroll
  for (int m = 0; m < 4; ++m)
#pragma unroll
    for (int n = 0; n < 4; ++n) acc[m][n] = (f32x4){0.f, 0.f, 0.f, 0.f};

  for (int k0 = 0; k0 < K; k0 += 64) {
    __syncthreads();
    stage_swz<128>(Abase + k0, K, As, tid);
    stage_swz<128>(Bbase + k0, K, Bs, tid);
    __syncthreads();
#pragma unroll
    for (int kk = 0; kk < 2; ++kk) {
      bf16x8 af[4], bfr[4];
#pragma unroll
      for (int m = 0; m < 4; ++m) af[m] = lds_read8_swz(As, wr * 64 + m * 16 + l15, kk * 4 + lg);
#pragma unroll
      for (int n = 0; n < 4; ++n) bfr[n] = lds_read8_swz(Bs, wc * 64 + n * 16 + l15, kk * 4 + lg);
#pragma unroll
      for (int m = 0; m < 4; ++m)
#pragma unroll
        for (int n = 0; n < 4; ++n)
          acc[m][n] = MFMA16(af[m], bfr[n], acc[m][n]);
    }
  }

  if (MODE == 2) {
    // V^T per head: Vt[((b*16+h)*64+d)*2048 + kv]; pack 4 consecutive kv (j).
#pragma unroll
    for (int m = 0; m < 4; ++m) {
      int row0 = bm * 128 + wr * 64 + m * 16 + lg * 4;
      int bb = row0 >> 11, kv = row0 & 2047;
#pragma unroll
      for (int n = 0; n < 4; ++n) {
        int col = bn * 128 + wc * 64 + n * 16 + l15;
        int hh = col >> 6, dd = col & 63;
        bf16x4 pk;
#pragma unroll
        for (int j = 0; j < 4; ++j) pk[j] = (bf16_t)acc[m][n][j];
        *reinterpret_cast<bf16x4*>(((bf16_t*)Cout) + (((size_t)((bb * 16 + hh) * 64 + dd)) << 11) + kv) = pk;
      }
    }
  } else {
#pragma unroll
    for (int m = 0; m < 4; ++m)
#pragma unroll
      for (int n = 0; n < 4; ++n)
#pragma unroll
        for (int j = 0; j < 4; ++j) {
          int row = bm * 128 + wr * 64 + m * 16 + lg * 4 + j;
          int col = bn * 128 + wc * 64 + n * 16 + l15;
          float v = acc[m][n][j];
          if (MODE == 0) ((bf16_t*)Cout)[(size_t)row * N + col] = (bf16_t)(v * scale);
          else           ((float*)Cout)[(size_t)row * N + col] = v + bias[col];
        }
  }
}

// ---------------- fused flash attention (swapped 16x16, lane-local softmax) --
// grid (NQ/64, HEADS, B) XCD-swizzled; 4 waves x 16 q (q = wid*16 + l15).
// S^T = mfma(kf, qf): lane col = its q; rows = kv (C-map row=4lg+j, R0-verified).
// Softmax: 15 lane-local max/adds + shfl_xor(16,32) only. P^T stored via
// 4x ds_write_b64 into pad-free row-rotated Ps, re-read as PV B-operand.
// O^T = mfma(vf, pf): lane keeps its q; all state lane-local.
// Q pre-scaled by 0.125*log2(e); exp2-domain softmax. LDS = 40960B (4 blk/CU).
__global__ __launch_bounds__(256) void attn_fused(const bf16_t* __restrict__ Qp,
                                                  const bf16_t* __restrict__ Kp,
                                                  const bf16_t* __restrict__ Vt,
                                                  bf16_t* __restrict__ Xa) {
  __shared__ __align__(16) bf16_t Ks[2][64 * 64];
  __shared__ __align__(16) bf16_t Vs[2][64 * 64];
  __shared__ __align__(16) bf16_t Ps[4][16 * 64];   // per-wave, pad-free, row-rotated
  const int tid = threadIdx.x;
  const int lane = tid & 63, wid = tid >> 6;
  const int l15 = lane & 15, lg = lane >> 4;
  const int rot = (l15 & 7) * 8;                    // per-row rotation (elements)

  // bijective XCD swizzle over 1024 workgroups: XCD k hosts 4 heads x 1 batch
  int id = blockIdx.x + 32 * (blockIdx.y + 16 * blockIdx.z);
  int swz = (id & 7) * 128 + (id >> 3);
  const int bx = swz & 31, h = (swz >> 5) & 15, b = swz >> 9;
  const int q0 = bx * 64;

  const bf16_t* qbase = Qp + ((size_t)(b * NQ + q0)) * DIM + h * HD;
  const bf16_t* kbase = Kp + ((size_t)b * NKK) * DIM + h * HD;
  const bf16_t* vbase = Vt + ((size_t)((b * HEADS + h) * HD)) * NKK;

  // ---- stage Q (64x64, reusing Ks[0]) and hoist per-wave fragments ----
  stage_swz<64>(qbase, DIM, &Ks[0][0], tid);
  __syncthreads();
  bf16x8 qf[2];
  qf[0] = lds_read8_swz(&Ks[0][0], wid * 16 + l15, lg);
  qf[1] = lds_read8_swz(&Ks[0][0], wid * 16 + l15, 4 + lg);
  __syncthreads();   // qf reads drained before K restage

  float m_ = -1e30f, l_ = 0.f;
  f32x4 o[4];
#pragma unroll
  for (int n = 0; n < 4; ++n) o[n] = (f32x4){0.f, 0.f, 0.f, 0.f};

  // prologue: stage tile 0
  stage_swz<64>(kbase, DIM, &Ks[0][0], tid);
  stage_swz<64>(vbase, NKK, &Vs[0][0], tid);
  __syncthreads();

  int cur = 0;
  for (int it = 0; it < NKK / 64; ++it) {
    // issue next tile early; HBM latency hides under QK^T/softmax/PV
    if (it + 1 < NKK / 64) {
      stage_swz<64>(kbase + (size_t)(it + 1) * 64 * DIM, DIM, &Ks[cur ^ 1][0], tid);
      stage_swz<64>(vbase + (it + 1) * 64, NKK, &Vs[cur ^ 1][0], tid);
    }
    const bf16_t* kl = &Ks[cur][0];
    const bf16_t* vl = &Vs[cur][0];

    // ---- S^T = K Q^T (lane: col = q, reg j of s[t] = kv 16t+4lg+j) ----
    f32x4 s[4];
#pragma unroll
    for (int t = 0; t < 4; ++t) s[t] = (f32x4){0.f, 0.f, 0.f, 0.f};
    __builtin_amdgcn_s_setprio(1);
#pragma unroll
    for (int t = 0; t < 4; ++t) {
      bf16x8 kf0 = lds_read8_swz(kl, t * 16 + l15, lg);
      bf16x8 kf1 = lds_read8_swz(kl, t * 16 + l15, 4 + lg);
      s[t] = MFMA16(kf0, qf[0], s[t]);
      s[t] = MFMA16(kf1, qf[1], s[t]);
    }
    __builtin_amdgcn_s_setprio(0);

    // ---- online softmax: one q per lane; 2 shuffle levels only ----
    float rm = s[0][0];
#pragma unroll
    for (int t = 0; t < 4; ++t)
#pragma unroll
      for (int j = 0; j < 4; ++j) rm = fmaxf(rm, s[t][j]);
    rm = fmaxf(rm, __shfl_xor(rm, 16));
    rm = fmaxf(rm, __shfl_xor(rm, 32));
    float mn = fmaxf(m_, rm);
    float alpha = exp2f(m_ - mn);
    m_ = mn;
#pragma unroll
    for (int n = 0; n < 4; ++n)
#pragma unroll
      for (int j = 0; j < 4; ++j) o[n][j] *= alpha;
    float rs = 0.f;
#pragma unroll
    for (int t = 0; t < 4; ++t)
#pragma unroll
      for (int j = 0; j < 4; ++j) {
        float p = exp2f(s[t][j] - mn);
        s[t][j] = p;
        rs += p;
      }
    rs += __shfl_xor(rs, 16);
    rs += __shfl_xor(rs, 32);
    l_ = l_ * alpha + rs;

    // ---- P^T -> per-wave LDS: row = q (l15), col = kv rotated by 8*(l15&7) ----
    bf16_t* Pw = &Ps[wid][0];
#pragma unroll
    for (int t = 0; t < 4; ++t) {
      unsigned w0 = cvtpk_bf16(s[t][0], s[t][1]);
      unsigned w1 = cvtpk_bf16(s[t][2], s[t][3]);
      int col = (16 * t + 4 * lg + rot) & 63;
      u32x2 pk2 = {w0, w1};
      *reinterpret_cast<u32x2*>(reinterpret_cast<char*>(Pw) + l15 * 128 + col * 2) = pk2;
    }
    asm volatile("s_waitcnt lgkmcnt(0)" ::: "memory");
    bf16x8 pf[2];
#pragma unroll
    for (int kt = 0; kt < 2; ++kt) {
      int col = (32 * kt + 8 * lg + rot) & 63;
      pf[kt] = *reinterpret_cast<const bf16x8*>(reinterpret_cast<const char*>(Pw) + l15 * 128 + col * 2);
    }

    // ---- O^T += V^T P^T (A = vf rows d, B = pf cols q; lane keeps its q) ----
    __builtin_amdgcn_s_setprio(1);
#pragma unroll
    for (int n = 0; n < 4; ++n) {
#pragma unroll
      for (int kt = 0; kt < 2; ++kt) {
        bf16x8 vf = lds_read8_swz(vl, n * 16 + l15, 4 * kt + lg);
        o[n] = MFMA16(vf, pf[kt], o[n]);
      }
    }
    __builtin_amdgcn_s_setprio(0);

    __syncthreads();   // drains vmcnt(0): next tile staged; everyone done with cur
    cur ^= 1;
  }

  // ---- epilogue: normalize, store (lane's q fixed; d = n*16 + 4lg + j) ----
  float inv = 1.f / l_;
  int q = q0 + wid * 16 + l15;
  bf16_t* ob = Xa + ((size_t)(b * NQ + q)) * DIM + h * HD;
#pragma unroll
  for (int n = 0; n < 4; ++n) {
    bf16x4 pk;
#pragma unroll
    for (int j = 0; j < 4; ++j) pk[j] = (bf16_t)(o[n][j] * inv);
    *reinterpret_cast<bf16x4*>(ob + n * 16 + 4 * lg) = pk;
  }
}

// ---------------- launcher ----------------
extern "C" void kernel_launch(void* const* d_in, const int* in_sizes, int n_in,
                              void* d_out, int out_size, void* d_ws, size_t ws_size,
                              hipStream_t stream) {
  (void)in_sizes; (void)n_in; (void)out_size; (void)ws_size;
  const float* q  = (const float*)d_in[0];
  const float* k  = (const float*)d_in[1];
  const float* v  = (const float*)d_in[2];
  const float* Wq = (const float*)d_in[5];
  const float* Wk = (const float*)d_in[6];
  const float* Wv = (const float*)d_in[7];
  const float* Wo = (const float*)d_in[8];
  const float* bo = (const float*)d_in[9];
  float* out = (float*)d_out;

  bf16_t* ws = (bf16_t*)d_ws;
  const size_t SZ_IN = (size_t)MROWS * DIM;  // 4M elems
  const size_t SZ_W  = (size_t)DIM * DIM;    // 1M elems
  bf16_t* qb  = ws;
  bf16_t* kb  = qb  + SZ_IN;
  bf16_t* vb  = kb  + SZ_IN;
  bf16_t* wqb = vb  + SZ_IN;
  bf16_t* wkb = wqb + SZ_W;
  bf16_t* wvb = wkb + SZ_W;
  bf16_t* wob = wvb + SZ_W;
  bf16_t* Qp  = wob + SZ_W;
  bf16_t* Kp  = Qp  + SZ_IN;
  bf16_t* Vtp = Kp  + SZ_IN;
  bf16_t* Xa  = qb;  // alias: qb dead after Q projection (stream-ordered)

  cvt_f32_bf16<<<dim3((unsigned)(SZ_IN / 1024)), 256, 0, stream>>>(q, qb, (int)(SZ_IN / 4));
  cvt_f32_bf16<<<dim3((unsigned)(SZ_IN / 1024)), 256, 0, stream>>>(k, kb, (int)(SZ_IN / 4));
  cvt_f32_bf16<<<dim3((unsigned)(SZ_IN / 1024)), 256, 0, stream>>>(v, vb, (int)(SZ_IN / 4));
  cvt_f32_bf16<<<dim3((unsigned)(SZ_W / 1024)), 256, 0, stream>>>(Wq, wqb, (int)(SZ_W / 4));
  cvt_f32_bf16<<<dim3((unsigned)(SZ_W / 1024)), 256, 0, stream>>>(Wk, wkb, (int)(SZ_W / 4));
  cvt_f32_bf16<<<dim3((unsigned)(SZ_W / 1024)), 256, 0, stream>>>(Wv, wvb, (int)(SZ_W / 4));
  cvt_f32_bf16<<<dim3((unsigned)(SZ_W / 1024)), 256, 0, stream>>>(Wo, wob, (int)(SZ_W / 4));

  dim3 gg(DIM / 128, MROWS / 128);  // (8, 32)
  // Q projection pre-scaled by 0.125 * log2(e) for the exp2-domain softmax
  gemm_bt<0><<<gg, 256, 0, stream>>>(qb, wqb, (void*)Qp, nullptr, MROWS, DIM, DIM, 0.18033688011112042f);
  gemm_bt<0><<<gg, 256, 0, stream>>>(kb, wkb, (void*)Kp, nullptr, MROWS, DIM, DIM, 1.0f);
  gemm_bt<2><<<gg, 256, 0, stream>>>(vb, wvb, (void*)Vtp, nullptr, MROWS, DIM, DIM, 1.0f);

  attn_fused<<<dim3(NQ / 64, HEADS, NB), 256, 0, stream>>>(Qp, Kp, Vtp, Xa);

  gemm_bt<1><<<gg, 256, 0, stream>>>(Xa, wob, (void*)out, bo, MROWS, DIM, DIM, 1.0f);
}

// Round 8
// 170.323 us; speedup vs baseline: 1.5108x; 1.2026x over previous
//
#include <hip/hip_runtime.h>
#include <hip/hip_bf16.h>
#include <stdint.h>

typedef __bf16 bf16_t;
typedef __bf16 bf16x4 __attribute__((ext_vector_type(4)));
typedef __bf16 bf16x8 __attribute__((ext_vector_type(8)));
typedef float  f32x4  __attribute__((ext_vector_type(4)));
typedef unsigned u32x2 __attribute__((ext_vector_type(2)));

#define MFMA16(a,b,c) __builtin_amdgcn_mfma_f32_16x16x32_bf16((a),(b),(c),0,0,0)

static constexpr int DIM = 1024, HEADS = 16, HD = 64, NB = 2, NQ = 2048, NKK = 2048;
static constexpr int MROWS = NB * NQ; // 4096 token rows
static constexpr float SCALE_Q = 0.18033688011112042f; // 0.125 * log2(e)

// ---------------- fused f32 -> bf16 convert (all 7 tensors, 1 launch) -------
// segments: 0-3 q, 4-7 k, 8-11 v (1M float4 each /4), 12-15 Wq,Wk,Wv,Wo (256K)
__global__ void cvt_all(const float* __restrict__ q, const float* __restrict__ k,
                        const float* __restrict__ v, const float* __restrict__ wq,
                        const float* __restrict__ wk, const float* __restrict__ wv,
                        const float* __restrict__ wo,
                        bf16_t* qb, bf16_t* kb, bf16_t* vb,
                        bf16_t* wqb, bf16_t* wkb, bf16_t* wvb, bf16_t* wob) {
  const int seg = blockIdx.y;
  const float* src; bf16_t* dst;
  size_t base;
  if (seg < 12) {
    int t = seg >> 2;                       // 0=q 1=k 2=v
    src = t == 0 ? q : t == 1 ? k : v;
    dst = t == 0 ? qb : t == 1 ? kb : vb;
    base = (size_t)(seg & 3) * 262144;      // quarter of 1M float4
  } else {
    int t = seg - 12;
    src = t == 0 ? wq : t == 1 ? wk : t == 2 ? wv : wo;
    dst = t == 0 ? wqb : t == 1 ? wkb : t == 2 ? wvb : wob;
    base = 0;
  }
  size_t i = base + blockIdx.x * 256 + threadIdx.x;
  float4 val = reinterpret_cast<const float4*>(src)[i];
  bf16x4 o;
  o[0] = (bf16_t)val.x; o[1] = (bf16_t)val.y; o[2] = (bf16_t)val.z; o[3] = (bf16_t)val.w;
  *reinterpret_cast<bf16x4*>(dst + i * 4) = o;
}

// ---------------- LDS staging with chunk-XOR swizzle ----------------
template<int ROWS>
__device__ __forceinline__ void stage_swz(const bf16_t* gbase, int gstride, bf16_t* lds, int tid) {
#pragma unroll
  for (int c = 0; c < ROWS / 32; ++c) {          // 256 chunks per iteration
    int p = c * 256 + tid;                        // 16B-chunk index
    int r = p >> 3, x = p & 7;
    const bf16_t* src = gbase + (size_t)r * gstride + ((x ^ (r & 7)) << 3);
    __builtin_amdgcn_global_load_lds(
        (const __attribute__((address_space(1))) void*)src,
        (__attribute__((address_space(3))) void*)(lds + (p << 3)),
        16, 0, 0);
  }
}

__device__ __forceinline__ bf16x8 lds_read8_swz(const bf16_t* lds, int row, int chunk) {
  int sc = chunk ^ (row & 7);
  return *reinterpret_cast<const bf16x8*>(lds + row * 64 + (sc << 3));
}

__device__ __forceinline__ unsigned cvtpk_bf16(float lo, float hi) {
  unsigned r;
  asm("v_cvt_pk_bf16_f32 %0, %1, %2" : "=v"(r) : "v"(lo), "v"(hi));
  return r;
}

// ---------------- fused QKV projection GEMM --------------------------------
// CROSS-attention: each projection has its OWN token input.
// bn 0-7: Qp = qb @ Wq^T (scaled SCALE_Q); 8-15: Kp = kb @ Wk^T;
// 16-23: Vt = vb @ Wv^T scattered to per-head-transposed layout (B,H,Dh,NK).
__global__ __launch_bounds__(256) void gemm_qkv(const bf16_t* __restrict__ qb,
                                                const bf16_t* __restrict__ kb,
                                                const bf16_t* __restrict__ vb,
                                                const bf16_t* __restrict__ Wq,
                                                const bf16_t* __restrict__ Wk,
                                                const bf16_t* __restrict__ Wv,
                                                bf16_t* __restrict__ Qp,
                                                bf16_t* __restrict__ Kp,
                                                bf16_t* __restrict__ Vt) {
  constexpr int K = DIM, N = DIM;
  __shared__ __align__(16) bf16_t As[128 * 64];
  __shared__ __align__(16) bf16_t Bs[128 * 64];
  const int tid = threadIdx.x;
  const int lane = tid & 63, wid = tid >> 6;
  const int l15 = lane & 15, lg = lane >> 4;
  const int wr = wid >> 1, wc = wid & 1;
  const int bn = blockIdx.x, bm = blockIdx.y;
  const int sel = bn >> 3, bnl = bn & 7;

  const bf16_t* A  = sel == 0 ? qb : sel == 1 ? kb : vb;   // <-- the R6/R7 bug fix
  const bf16_t* Bt = sel == 0 ? Wq : sel == 1 ? Wk : Wv;
  const bf16_t* Abase = A + (size_t)(bm * 128) * K;
  const bf16_t* Bbase = Bt + (size_t)(bnl * 128) * K;

  f32x4 acc[4][4];
#pragma unroll
  for (int m = 0; m < 4; ++m)
#pragma unroll
    for (int n = 0; n < 4; ++n) acc[m][n] = (f32x4){0.f, 0.f, 0.f, 0.f};

  for (int k0 = 0; k0 < K; k0 += 64) {
    __syncthreads();
    stage_swz<128>(Abase + k0, K, As, tid);
    stage_swz<128>(Bbase + k0, K, Bs, tid);
    __syncthreads();
#pragma unroll
    for (int kk = 0; kk < 2; ++kk) {
      bf16x8 af[4], bfr[4];
#pragma unroll
      for (int m = 0; m < 4; ++m) af[m] = lds_read8_swz(As, wr * 64 + m * 16 + l15, kk * 4 + lg);
#pragma unroll
      for (int n = 0; n < 4; ++n) bfr[n] = lds_read8_swz(Bs, wc * 64 + n * 16 + l15, kk * 4 + lg);
#pragma unroll
      for (int m = 0; m < 4; ++m)
#pragma unroll
        for (int n = 0; n < 4; ++n)
          acc[m][n] = MFMA16(af[m], bfr[n], acc[m][n]);
    }
  }

  if (sel == 2) {
    // V^T per head: Vt[((b*16+h)*64+d)*2048 + kv]
#pragma unroll
    for (int m = 0; m < 4; ++m) {
      int row0 = bm * 128 + wr * 64 + m * 16 + lg * 4;
      int bb = row0 >> 11, kv = row0 & 2047;
#pragma unroll
      for (int n = 0; n < 4; ++n) {
        int col = bnl * 128 + wc * 64 + n * 16 + l15;
        int hh = col >> 6, dd = col & 63;
        bf16x4 pk;
#pragma unroll
        for (int j = 0; j < 4; ++j) pk[j] = (bf16_t)acc[m][n][j];
        *reinterpret_cast<bf16x4*>(Vt + (((size_t)((bb * 16 + hh) * 64 + dd)) << 11) + kv) = pk;
      }
    }
  } else {
    bf16_t* Cout = sel == 0 ? Qp : Kp;
    const float scale = sel == 0 ? SCALE_Q : 1.0f;
#pragma unroll
    for (int m = 0; m < 4; ++m)
#pragma unroll
      for (int n = 0; n < 4; ++n)
#pragma unroll
        for (int j = 0; j < 4; ++j) {
          int row = bm * 128 + wr * 64 + m * 16 + lg * 4 + j;
          int col = bnl * 128 + wc * 64 + n * 16 + l15;
          Cout[(size_t)row * N + col] = (bf16_t)(acc[m][n][j] * scale);
        }
  }
}

// ---------------- output projection GEMM (f32 + bias) ----------------------
__global__ __launch_bounds__(256) void gemm_out(const bf16_t* __restrict__ A,
                                                const bf16_t* __restrict__ Bt,
                                                float* __restrict__ Cout,
                                                const float* __restrict__ bias) {
  constexpr int K = DIM, N = DIM;
  __shared__ __align__(16) bf16_t As[128 * 64];
  __shared__ __align__(16) bf16_t Bs[128 * 64];
  const int tid = threadIdx.x;
  const int lane = tid & 63, wid = tid >> 6;
  const int l15 = lane & 15, lg = lane >> 4;
  const int wr = wid >> 1, wc = wid & 1;
  const int bn = blockIdx.x, bm = blockIdx.y;

  const bf16_t* Abase = A + (size_t)(bm * 128) * K;
  const bf16_t* Bbase = Bt + (size_t)(bn * 128) * K;

  f32x4 acc[4][4];
#pragma unroll
  for (int m = 0; m < 4; ++m)
#pragma unroll
    for (int n = 0; n < 4; ++n) acc[m][n] = (f32x4){0.f, 0.f, 0.f, 0.f};

  for (int k0 = 0; k0 < K; k0 += 64) {
    __syncthreads();
    stage_swz<128>(Abase + k0, K, As, tid);
    stage_swz<128>(Bbase + k0, K, Bs, tid);
    __syncthreads();
#pragma unroll
    for (int kk = 0; kk < 2; ++kk) {
      bf16x8 af[4], bfr[4];
#pragma unroll
      for (int m = 0; m < 4; ++m) af[m] = lds_read8_swz(As, wr * 64 + m * 16 + l15, kk * 4 + lg);
#pragma unroll
      for (int n = 0; n < 4; ++n) bfr[n] = lds_read8_swz(Bs, wc * 64 + n * 16 + l15, kk * 4 + lg);
#pragma unroll
      for (int m = 0; m < 4; ++m)
#pragma unroll
        for (int n = 0; n < 4; ++n)
          acc[m][n] = MFMA16(af[m], bfr[n], acc[m][n]);
    }
  }

#pragma unroll
  for (int m = 0; m < 4; ++m)
#pragma unroll
    for (int n = 0; n < 4; ++n)
#pragma unroll
      for (int j = 0; j < 4; ++j) {
        int row = bm * 128 + wr * 64 + m * 16 + lg * 4 + j;
        int col = bn * 128 + wc * 64 + n * 16 + l15;
        Cout[(size_t)row * N + col] = acc[m][n][j] + bias[col];
      }
}

// ---------------- fused flash attention ------------------------------------
// QBLK=128: 4 waves x 32 q (2 q-groups of 16; one q per lane per group).
// K/V fragments read once per tile, reused across both q-groups.
// S^T = mfma(kf, qf[g]); softmax lane-local + shfl_xor(16,32); defer-max.
// P^T via cvt_pk -> rotated pad-free LDS -> b128 reads; O^T = mfma(vf, pf).
// Q pre-scaled by 0.125*log2(e); exp2-domain. LDS = 48KB; grid 512 (2/CU).
__global__ __launch_bounds__(256) void attn_fused(const bf16_t* __restrict__ Qp,
                                                  const bf16_t* __restrict__ Kp,
                                                  const bf16_t* __restrict__ Vt,
                                                  bf16_t* __restrict__ Xa) {
  __shared__ __align__(16) bf16_t Ks[2][64 * 64];
  __shared__ __align__(16) bf16_t Vs[2][64 * 64];
  __shared__ __align__(16) bf16_t Ps[4][32 * 64];   // per-wave P^T, row-rotated
  const int tid = threadIdx.x;
  const int lane = tid & 63, wid = tid >> 6;
  const int l15 = lane & 15, lg = lane >> 4;
  const int rot = (l15 & 7) * 8;

  // bijective XCD swizzle over 512 workgroups: XCD k hosts heads 4k..4k+3
  int id = blockIdx.x + 16 * (blockIdx.y + 16 * blockIdx.z);
  int swz = (id & 7) * 64 + (id >> 3);
  const int bx = swz & 15, h = (swz >> 4) & 15, b = swz >> 8;
  const int q0 = bx * 128;

  const bf16_t* qbase = Qp + ((size_t)(b * NQ + q0)) * DIM + h * HD;
  const bf16_t* kbase = Kp + ((size_t)b * NKK) * DIM + h * HD;
  const bf16_t* vbase = Vt + ((size_t)((b * HEADS + h) * HD)) * NKK;

  // ---- stage Q (128x64 = 16KB across Ks[0..1]) and hoist fragments ----
  stage_swz<128>(qbase, DIM, &Ks[0][0], tid);
  __syncthreads();
  bf16x8 qf[2][2];
#pragma unroll
  for (int g = 0; g < 2; ++g) {
    qf[g][0] = lds_read8_swz(&Ks[0][0], wid * 32 + g * 16 + l15, lg);
    qf[g][1] = lds_read8_swz(&Ks[0][0], wid * 32 + g * 16 + l15, 4 + lg);
  }
  __syncthreads();   // qf reads drained before K restage

  float m_[2] = {-1e30f, -1e30f}, l_[2] = {0.f, 0.f};
  f32x4 o[2][4];
#pragma unroll
  for (int g = 0; g < 2; ++g)
#pragma unroll
    for (int n = 0; n < 4; ++n) o[g][n] = (f32x4){0.f, 0.f, 0.f, 0.f};

  // prologue: stage tile 0
  stage_swz<64>(kbase, DIM, &Ks[0][0], tid);
  stage_swz<64>(vbase, NKK, &Vs[0][0], tid);
  __syncthreads();

  int cur = 0;
  for (int it = 0; it < NKK / 64; ++it) {
    if (it + 1 < NKK / 64) {
      stage_swz<64>(kbase + (size_t)(it + 1) * 64 * DIM, DIM, &Ks[cur ^ 1][0], tid);
      stage_swz<64>(vbase + (it + 1) * 64, NKK, &Vs[cur ^ 1][0], tid);
    }
    const bf16_t* kl = &Ks[cur][0];
    const bf16_t* vl = &Vs[cur][0];

    // ---- K fragments (read once, reused for both q-groups) ----
    bf16x8 kf0[4], kf1[4];
#pragma unroll
    for (int t = 0; t < 4; ++t) {
      kf0[t] = lds_read8_swz(kl, t * 16 + l15, lg);
      kf1[t] = lds_read8_swz(kl, t * 16 + l15, 4 + lg);
    }

    // ---- S^T = K Q^T per group (lane col = q; reg j of s[g][t] = kv 16t+4lg+j)
    f32x4 s[2][4];
#pragma unroll
    for (int g = 0; g < 2; ++g)
#pragma unroll
      for (int t = 0; t < 4; ++t) s[g][t] = (f32x4){0.f, 0.f, 0.f, 0.f};
    __builtin_amdgcn_s_setprio(1);
#pragma unroll
    for (int g = 0; g < 2; ++g)
#pragma unroll
      for (int t = 0; t < 4; ++t) {
        s[g][t] = MFMA16(kf0[t], qf[g][0], s[g][t]);
        s[g][t] = MFMA16(kf1[t], qf[g][1], s[g][t]);
      }
    __builtin_amdgcn_s_setprio(0);

    // ---- online softmax per group: lane-local + 2 shuffles; defer-max ----
#pragma unroll
    for (int g = 0; g < 2; ++g) {
      float rm = s[g][0][0];
#pragma unroll
      for (int t = 0; t < 4; ++t)
#pragma unroll
        for (int j = 0; j < 4; ++j) rm = fmaxf(rm, s[g][t][j]);
      rm = fmaxf(rm, __shfl_xor(rm, 16));
      rm = fmaxf(rm, __shfl_xor(rm, 32));
      if (!__all(rm <= m_[g] + 8.f)) {       // defer-max (T13)
        float mn = fmaxf(m_[g], rm);
        float al = exp2f(m_[g] - mn);
        m_[g] = mn;
        l_[g] *= al;
#pragma unroll
        for (int n = 0; n < 4; ++n)
#pragma unroll
          for (int j = 0; j < 4; ++j) o[g][n][j] *= al;
      }
      float rs = 0.f;
#pragma unroll
      for (int t = 0; t < 4; ++t)
#pragma unroll
        for (int j = 0; j < 4; ++j) {
          float p = exp2f(s[g][t][j] - m_[g]);
          s[g][t][j] = p;
          rs += p;
        }
      rs += __shfl_xor(rs, 16);
      rs += __shfl_xor(rs, 32);
      l_[g] += rs;
    }

    // ---- P^T -> per-wave LDS (row = g*16+l15, col = kv rotated) ----
    bf16_t* Pw = &Ps[wid][0];
#pragma unroll
    for (int g = 0; g < 2; ++g)
#pragma unroll
      for (int t = 0; t < 4; ++t) {
        unsigned w0 = cvtpk_bf16(s[g][t][0], s[g][t][1]);
        unsigned w1 = cvtpk_bf16(s[g][t][2], s[g][t][3]);
        int col = (16 * t + 4 * lg + rot) & 63;
        u32x2 pk2 = {w0, w1};
        *reinterpret_cast<u32x2*>(reinterpret_cast<char*>(Pw) + (g * 16 + l15) * 128 + col * 2) = pk2;
      }
    asm volatile("s_waitcnt lgkmcnt(0)" ::: "memory");
    bf16x8 pf[2][2];
#pragma unroll
    for (int g = 0; g < 2; ++g)
#pragma unroll
      for (int kt = 0; kt < 2; ++kt) {
        int col = (32 * kt + 8 * lg + rot) & 63;
        pf[g][kt] = *reinterpret_cast<const bf16x8*>(
            reinterpret_cast<const char*>(Pw) + (g * 16 + l15) * 128 + col * 2);
      }

    // ---- O^T += V^T P^T (V frags read once, reused for both groups) ----
    __builtin_amdgcn_s_setprio(1);
#pragma unroll
    for (int n = 0; n < 4; ++n) {
      bf16x8 vf0 = lds_read8_swz(vl, n * 16 + l15, lg);
      bf16x8 vf1 = lds_read8_swz(vl, n * 16 + l15, 4 + lg);
#pragma unroll
      for (int g = 0; g < 2; ++g) {
        o[g][n] = MFMA16(vf0, pf[g][0], o[g][n]);
        o[g][n] = MFMA16(vf1, pf[g][1], o[g][n]);
      }
    }
    __builtin_amdgcn_s_setprio(0);

    __syncthreads();   // drains vmcnt(0): next tile staged; everyone done with cur
    cur ^= 1;
  }

  // ---- epilogue: normalize, store (lane's q fixed; d = n*16 + 4lg + j) ----
#pragma unroll
  for (int g = 0; g < 2; ++g) {
    float inv = 1.f / l_[g];
    int q = q0 + wid * 32 + g * 16 + l15;
    bf16_t* ob = Xa + ((size_t)(b * NQ + q)) * DIM + h * HD;
#pragma unroll
    for (int n = 0; n < 4; ++n) {
      bf16x4 pk;
#pragma unroll
      for (int j = 0; j < 4; ++j) pk[j] = (bf16_t)(o[g][n][j] * inv);
      *reinterpret_cast<bf16x4*>(ob + n * 16 + 4 * lg) = pk;
    }
  }
}

// ---------------- launcher ----------------
extern "C" void kernel_launch(void* const* d_in, const int* in_sizes, int n_in,
                              void* d_out, int out_size, void* d_ws, size_t ws_size,
                              hipStream_t stream) {
  (void)in_sizes; (void)n_in; (void)out_size; (void)ws_size;
  const float* q  = (const float*)d_in[0];
  const float* k  = (const float*)d_in[1];
  const float* v  = (const float*)d_in[2];
  const float* Wq = (const float*)d_in[5];
  const float* Wk = (const float*)d_in[6];
  const float* Wv = (const float*)d_in[7];
  const float* Wo = (const float*)d_in[8];
  const float* bo = (const float*)d_in[9];
  float* out = (float*)d_out;

  bf16_t* ws = (bf16_t*)d_ws;
  const size_t SZ_IN = (size_t)MROWS * DIM;  // 4M elems
  const size_t SZ_W  = (size_t)DIM * DIM;    // 1M elems
  bf16_t* qb  = ws;
  bf16_t* kb  = qb  + SZ_IN;
  bf16_t* vb  = kb  + SZ_IN;
  bf16_t* wqb = vb  + SZ_IN;
  bf16_t* wkb = wqb + SZ_W;
  bf16_t* wvb = wkb + SZ_W;
  bf16_t* wob = wvb + SZ_W;
  bf16_t* Qp  = wob + SZ_W;
  bf16_t* Kp  = Qp  + SZ_IN;
  bf16_t* Vtp = Kp  + SZ_IN;
  bf16_t* Xa  = qb;  // alias: qb dead after QKV projection (stream-ordered)

  // 1 launch: all f32->bf16 converts (grid.x covers 256K float4 per segment)
  cvt_all<<<dim3(1024, 16), 256, 0, stream>>>(q, k, v, Wq, Wk, Wv, Wo,
                                              qb, kb, vb, wqb, wkb, wvb, wob);

  // 1 launch: fused QKV projection (each projection from its OWN token input)
  gemm_qkv<<<dim3(24, MROWS / 128), 256, 0, stream>>>(qb, kb, vb, wqb, wkb, wvb,
                                                      Qp, Kp, Vtp);

  attn_fused<<<dim3(NQ / 128, HEADS, NB), 256, 0, stream>>>(Qp, Kp, Vtp, Xa);

  gemm_out<<<dim3(DIM / 128, MROWS / 128), 256, 0, stream>>>(Xa, wob, out, bo);
}

// Round 9
// 164.733 us; speedup vs baseline: 1.5621x; 1.0339x over previous
//
#include <hip/hip_runtime.h>
#include <hip/hip_bf16.h>
#include <stdint.h>

typedef __bf16 bf16_t;
typedef __bf16 bf16x4 __attribute__((ext_vector_type(4)));
typedef __bf16 bf16x8 __attribute__((ext_vector_type(8)));
typedef float  f32x4  __attribute__((ext_vector_type(4)));
typedef unsigned u32x2 __attribute__((ext_vector_type(2)));

#define MFMA16(a,b,c) __builtin_amdgcn_mfma_f32_16x16x32_bf16((a),(b),(c),0,0,0)

static constexpr int DIM = 1024, HEADS = 16, HD = 64, NB = 2, NQ = 2048, NKK = 2048;
static constexpr int MROWS = NB * NQ; // 4096 token rows
static constexpr float SCALE_Q = 0.18033688011112042f; // 0.125 * log2(e)

// ---------------- fused f32 -> bf16 convert (all 7 tensors, 1 launch) -------
__global__ void cvt_all(const float* __restrict__ q, const float* __restrict__ k,
                        const float* __restrict__ v, const float* __restrict__ wq,
                        const float* __restrict__ wk, const float* __restrict__ wv,
                        const float* __restrict__ wo,
                        bf16_t* qb, bf16_t* kb, bf16_t* vb,
                        bf16_t* wqb, bf16_t* wkb, bf16_t* wvb, bf16_t* wob) {
  const int seg = blockIdx.y;
  const float* src; bf16_t* dst;
  size_t base;
  if (seg < 12) {
    int t = seg >> 2;                       // 0=q 1=k 2=v
    src = t == 0 ? q : t == 1 ? k : v;
    dst = t == 0 ? qb : t == 1 ? kb : vb;
    base = (size_t)(seg & 3) * 262144;      // quarter of 1M float4
  } else {
    int t = seg - 12;
    src = t == 0 ? wq : t == 1 ? wk : t == 2 ? wv : wo;
    dst = t == 0 ? wqb : t == 1 ? wkb : t == 2 ? wvb : wob;
    base = 0;
  }
  size_t i = base + blockIdx.x * 256 + threadIdx.x;
  float4 val = reinterpret_cast<const float4*>(src)[i];
  bf16x4 o;
  o[0] = (bf16_t)val.x; o[1] = (bf16_t)val.y; o[2] = (bf16_t)val.z; o[3] = (bf16_t)val.w;
  *reinterpret_cast<bf16x4*>(dst + i * 4) = o;
}

// ---------------- LDS staging with chunk-XOR swizzle ----------------
template<int ROWS>
__device__ __forceinline__ void stage_swz(const bf16_t* gbase, int gstride, bf16_t* lds, int tid) {
#pragma unroll
  for (int c = 0; c < ROWS / 32; ++c) {
    int p = c * 256 + tid;                        // 16B-chunk index
    int r = p >> 3, x = p & 7;
    const bf16_t* src = gbase + (size_t)r * gstride + ((x ^ (r & 7)) << 3);
    __builtin_amdgcn_global_load_lds(
        (const __attribute__((address_space(1))) void*)src,
        (__attribute__((address_space(3))) void*)(lds + (p << 3)),
        16, 0, 0);
  }
}

__device__ __forceinline__ bf16x8 lds_read8_swz(const bf16_t* lds, int row, int chunk) {
  int sc = chunk ^ (row & 7);
  return *reinterpret_cast<const bf16x8*>(lds + row * 64 + (sc << 3));
}

__device__ __forceinline__ unsigned cvtpk_bf16(float lo, float hi) {
  unsigned r;
  asm("v_cvt_pk_bf16_f32 %0, %1, %2" : "=v"(r) : "v"(lo), "v"(hi));
  return r;
}

// ---------------- fused QKV projection GEMM --------------------------------
// CROSS-attention: each projection has its OWN token input.
__global__ __launch_bounds__(256) void gemm_qkv(const bf16_t* __restrict__ qb,
                                                const bf16_t* __restrict__ kb,
                                                const bf16_t* __restrict__ vb,
                                                const bf16_t* __restrict__ Wq,
                                                const bf16_t* __restrict__ Wk,
                                                const bf16_t* __restrict__ Wv,
                                                bf16_t* __restrict__ Qp,
                                                bf16_t* __restrict__ Kp,
                                                bf16_t* __restrict__ Vt) {
  constexpr int K = DIM, N = DIM;
  __shared__ __align__(16) bf16_t As[128 * 64];
  __shared__ __align__(16) bf16_t Bs[128 * 64];
  const int tid = threadIdx.x;
  const int lane = tid & 63, wid = tid >> 6;
  const int l15 = lane & 15, lg = lane >> 4;
  const int wr = wid >> 1, wc = wid & 1;
  const int bn = blockIdx.x, bm = blockIdx.y;
  const int sel = bn >> 3, bnl = bn & 7;

  const bf16_t* A  = sel == 0 ? qb : sel == 1 ? kb : vb;
  const bf16_t* Bt = sel == 0 ? Wq : sel == 1 ? Wk : Wv;
  const bf16_t* Abase = A + (size_t)(bm * 128) * K;
  const bf16_t* Bbase = Bt + (size_t)(bnl * 128) * K;

  f32x4 acc[4][4];
#pragma unroll
  for (int m = 0; m < 4; ++m)
#pragma unroll
    for (int n = 0; n < 4; ++n) acc[m][n] = (f32x4){0.f, 0.f, 0.f, 0.f};

  for (int k0 = 0; k0 < K; k0 += 64) {
    __syncthreads();
    stage_swz<128>(Abase + k0, K, As, tid);
    stage_swz<128>(Bbase + k0, K, Bs, tid);
    __syncthreads();
#pragma unroll
    for (int kk = 0; kk < 2; ++kk) {
      bf16x8 af[4], bfr[4];
#pragma unroll
      for (int m = 0; m < 4; ++m) af[m] = lds_read8_swz(As, wr * 64 + m * 16 + l15, kk * 4 + lg);
#pragma unroll
      for (int n = 0; n < 4; ++n) bfr[n] = lds_read8_swz(Bs, wc * 64 + n * 16 + l15, kk * 4 + lg);
#pragma unroll
      for (int m = 0; m < 4; ++m)
#pragma unroll
        for (int n = 0; n < 4; ++n)
          acc[m][n] = MFMA16(af[m], bfr[n], acc[m][n]);
    }
  }

  if (sel == 2) {
#pragma unroll
    for (int m = 0; m < 4; ++m) {
      int row0 = bm * 128 + wr * 64 + m * 16 + lg * 4;
      int bb = row0 >> 11, kv = row0 & 2047;
#pragma unroll
      for (int n = 0; n < 4; ++n) {
        int col = bnl * 128 + wc * 64 + n * 16 + l15;
        int hh = col >> 6, dd = col & 63;
        bf16x4 pk;
#pragma unroll
        for (int j = 0; j < 4; ++j) pk[j] = (bf16_t)acc[m][n][j];
        *reinterpret_cast<bf16x4*>(Vt + (((size_t)((bb * 16 + hh) * 64 + dd)) << 11) + kv) = pk;
      }
    }
  } else {
    bf16_t* Cout = sel == 0 ? Qp : Kp;
    const float scale = sel == 0 ? SCALE_Q : 1.0f;
#pragma unroll
    for (int m = 0; m < 4; ++m)
#pragma unroll
      for (int n = 0; n < 4; ++n)
#pragma unroll
        for (int j = 0; j < 4; ++j) {
          int row = bm * 128 + wr * 64 + m * 16 + lg * 4 + j;
          int col = bnl * 128 + wc * 64 + n * 16 + l15;
          Cout[(size_t)row * N + col] = (bf16_t)(acc[m][n][j] * scale);
        }
  }
}

// ---------------- output projection GEMM (f32 + bias) ----------------------
__global__ __launch_bounds__(256) void gemm_out(const bf16_t* __restrict__ A,
                                                const bf16_t* __restrict__ Bt,
                                                float* __restrict__ Cout,
                                                const float* __restrict__ bias) {
  constexpr int K = DIM, N = DIM;
  __shared__ __align__(16) bf16_t As[128 * 64];
  __shared__ __align__(16) bf16_t Bs[128 * 64];
  const int tid = threadIdx.x;
  const int lane = tid & 63, wid = tid >> 6;
  const int l15 = lane & 15, lg = lane >> 4;
  const int wr = wid >> 1, wc = wid & 1;
  const int bn = blockIdx.x, bm = blockIdx.y;

  const bf16_t* Abase = A + (size_t)(bm * 128) * K;
  const bf16_t* Bbase = Bt + (size_t)(bn * 128) * K;

  f32x4 acc[4][4];
#pragma unroll
  for (int m = 0; m < 4; ++m)
#pragma unroll
    for (int n = 0; n < 4; ++n) acc[m][n] = (f32x4){0.f, 0.f, 0.f, 0.f};

  for (int k0 = 0; k0 < K; k0 += 64) {
    __syncthreads();
    stage_swz<128>(Abase + k0, K, As, tid);
    stage_swz<128>(Bbase + k0, K, Bs, tid);
    __syncthreads();
#pragma unroll
    for (int kk = 0; kk < 2; ++kk) {
      bf16x8 af[4], bfr[4];
#pragma unroll
      for (int m = 0; m < 4; ++m) af[m] = lds_read8_swz(As, wr * 64 + m * 16 + l15, kk * 4 + lg);
#pragma unroll
      for (int n = 0; n < 4; ++n) bfr[n] = lds_read8_swz(Bs, wc * 64 + n * 16 + l15, kk * 4 + lg);
#pragma unroll
      for (int m = 0; m < 4; ++m)
#pragma unroll
        for (int n = 0; n < 4; ++n)
          acc[m][n] = MFMA16(af[m], bfr[n], acc[m][n]);
    }
  }

#pragma unroll
  for (int m = 0; m < 4; ++m)
#pragma unroll
    for (int n = 0; n < 4; ++n)
#pragma unroll
      for (int j = 0; j < 4; ++j) {
        int row = bm * 128 + wr * 64 + m * 16 + lg * 4 + j;
        int col = bn * 128 + wc * 64 + n * 16 + l15;
        Cout[(size_t)row * N + col] = acc[m][n][j] + bias[col];
      }
}

// ---------------- fused flash attention (R5 geometry + 2-tile pipeline) -----
// grid (NQ/64, HEADS, B) XCD-swizzled; 4 waves x 16 q (q = wid*16 + l15).
// PIPELINE: QK(t+1) is issued at the TOP of iter t (MFMA pipe), then
// softmax(t) runs on independent regs (VALU pipe) -> free overlap.
// Tile lifetimes: K(j) staged iter j-2, read (QK) iter j-1; V(j) staged
// iter j-1, read (PV) iter j. Both double-buffered; every buffer reuse is
// separated by exactly one __syncthreads. LDS = 40960B -> 4 blocks/CU.
__global__ __launch_bounds__(256) void attn_fused(const bf16_t* __restrict__ Qp,
                                                  const bf16_t* __restrict__ Kp,
                                                  const bf16_t* __restrict__ Vt,
                                                  bf16_t* __restrict__ Xa) {
  __shared__ __align__(16) bf16_t Ks[2][64 * 64];
  __shared__ __align__(16) bf16_t Vs[2][64 * 64];
  __shared__ __align__(16) bf16_t Ps[4][16 * 64];   // per-wave, pad-free, row-rotated
  const int tid = threadIdx.x;
  const int lane = tid & 63, wid = tid >> 6;
  const int l15 = lane & 15, lg = lane >> 4;
  const int rot = (l15 & 7) * 8;

  // bijective XCD swizzle over 1024 workgroups: XCD k hosts 4 heads x 1 batch
  int id = blockIdx.x + 32 * (blockIdx.y + 16 * blockIdx.z);
  int swz = (id & 7) * 128 + (id >> 3);
  const int bx = swz & 31, h = (swz >> 5) & 15, b = swz >> 9;
  const int q0 = bx * 64;

  const bf16_t* qbase = Qp + ((size_t)(b * NQ + q0)) * DIM + h * HD;
  const bf16_t* kbase = Kp + ((size_t)b * NKK) * DIM + h * HD;
  const bf16_t* vbase = Vt + ((size_t)((b * HEADS + h) * HD)) * NKK;

  // ---- stage Q (64x64, reusing Ks[0]) and hoist per-wave fragments ----
  stage_swz<64>(qbase, DIM, &Ks[0][0], tid);
  __syncthreads();
  bf16x8 qf[2];
  qf[0] = lds_read8_swz(&Ks[0][0], wid * 16 + l15, lg);
  qf[1] = lds_read8_swz(&Ks[0][0], wid * 16 + l15, 4 + lg);
  __syncthreads();   // qf reads drained before K restage

  float m_ = -1e30f, l_ = 0.f;
  f32x4 o[4];
#pragma unroll
  for (int n = 0; n < 4; ++n) o[n] = (f32x4){0.f, 0.f, 0.f, 0.f};

  constexpr int NT = NKK / 64;   // 32 kv tiles

  // QK helper: s[t] accumulates K-rows (16t+4lg+j) x lane's q column (l15)
#define QK_TILE(kl, sdst)                                              \
  do {                                                                 \
    __builtin_amdgcn_s_setprio(1);                                     \
    _Pragma("unroll")                                                  \
    for (int tt = 0; tt < 4; ++tt) {                                   \
      bf16x8 kf0 = lds_read8_swz((kl), tt * 16 + l15, lg);             \
      bf16x8 kf1 = lds_read8_swz((kl), tt * 16 + l15, 4 + lg);         \
      f32x4 a = (f32x4){0.f, 0.f, 0.f, 0.f};                           \
      a = MFMA16(kf0, qf[0], a);                                       \
      a = MFMA16(kf1, qf[1], a);                                       \
      (sdst)[tt] = a;                                                  \
    }                                                                  \
    __builtin_amdgcn_s_setprio(0);                                     \
  } while (0)

  // ---- prologue: K(0),V(0) staged; QK(0); K(1) staged ----
  stage_swz<64>(kbase, DIM, &Ks[0][0], tid);
  stage_swz<64>(vbase, NKK, &Vs[0][0], tid);
  __syncthreads();                       // K(0)/V(0) visible
  f32x4 scur[4];
  QK_TILE(&Ks[0][0], scur);              // S(0)
  stage_swz<64>(kbase + (size_t)64 * DIM, DIM, &Ks[1][0], tid);   // K(1)
  __syncthreads();                       // K(1) visible; all QK(0) reads done
                                         // (protects Ks[0] before iter-0 restage)

  for (int t = 0; t < NT; ++t) {
    // 1) issue next stages (latency hides under this whole iteration)
    if (t + 1 < NT) stage_swz<64>(vbase + (t + 1) * 64, NKK, &Vs[(t + 1) & 1][0], tid);
    if (t + 2 < NT) stage_swz<64>(kbase + (size_t)(t + 2) * 64 * DIM, DIM, &Ks[t & 1][0], tid);

    // 2) QK(t+1) early: MFMA pipe busy while softmax(t) runs on the VALU
    f32x4 snx[4];
    if (t + 1 < NT) QK_TILE(&Ks[(t + 1) & 1][0], snx);

    // 3) softmax(t) on scur: lane-local + shfl_xor(16,32); defer-max (T13)
    float rm = scur[0][0];
#pragma unroll
    for (int tt = 0; tt < 4; ++tt)
#pragma unroll
      for (int j = 0; j < 4; ++j) rm = fmaxf(rm, scur[tt][j]);
    rm = fmaxf(rm, __shfl_xor(rm, 16));
    rm = fmaxf(rm, __shfl_xor(rm, 32));
    if (!__all(rm <= m_ + 8.f)) {
      float mn = fmaxf(m_, rm);
      float al = exp2f(m_ - mn);
      m_ = mn;
      l_ *= al;
#pragma unroll
      for (int n = 0; n < 4; ++n)
#pragma unroll
        for (int j = 0; j < 4; ++j) o[n][j] *= al;
    }
    float rs = 0.f;
#pragma unroll
    for (int tt = 0; tt < 4; ++tt)
#pragma unroll
      for (int j = 0; j < 4; ++j) {
        float p = exp2f(scur[tt][j] - m_);
        scur[tt][j] = p;
        rs += p;
      }
    rs += __shfl_xor(rs, 16);
    rs += __shfl_xor(rs, 32);
    l_ += rs;

    // 4) P^T -> per-wave LDS: row = q (l15), col = kv rotated by 8*(l15&7)
    bf16_t* Pw = &Ps[wid][0];
#pragma unroll
    for (int tt = 0; tt < 4; ++tt) {
      unsigned w0 = cvtpk_bf16(scur[tt][0], scur[tt][1]);
      unsigned w1 = cvtpk_bf16(scur[tt][2], scur[tt][3]);
      int col = (16 * tt + 4 * lg + rot) & 63;
      u32x2 pk2 = {w0, w1};
      *reinterpret_cast<u32x2*>(reinterpret_cast<char*>(Pw) + l15 * 128 + col * 2) = pk2;
    }
    asm volatile("s_waitcnt lgkmcnt(0)" ::: "memory");
    bf16x8 pf[2];
#pragma unroll
    for (int kt = 0; kt < 2; ++kt) {
      int col = (32 * kt + 8 * lg + rot) & 63;
      pf[kt] = *reinterpret_cast<const bf16x8*>(reinterpret_cast<const char*>(Pw) + l15 * 128 + col * 2);
    }

    // 5) PV(t): O^T += V^T P^T from Vs[t&1]
    const bf16_t* vl = &Vs[t & 1][0];
    __builtin_amdgcn_s_setprio(1);
#pragma unroll
    for (int n = 0; n < 4; ++n) {
#pragma unroll
      for (int kt = 0; kt < 2; ++kt) {
        bf16x8 vf = lds_read8_swz(vl, n * 16 + l15, 4 * kt + lg);
        o[n] = MFMA16(vf, pf[kt], o[n]);
      }
    }
    __builtin_amdgcn_s_setprio(0);

    __syncthreads();   // drains staging vmcnt; all reads of cur buffers done
    if (t + 1 < NT) {
#pragma unroll
      for (int tt = 0; tt < 4; ++tt) scur[tt] = snx[tt];
    }
  }
#undef QK_TILE

  // ---- epilogue: normalize, store (lane's q fixed; d = n*16 + 4lg + j) ----
  float inv = 1.f / l_;
  int q = q0 + wid * 16 + l15;
  bf16_t* ob = Xa + ((size_t)(b * NQ + q)) * DIM + h * HD;
#pragma unroll
  for (int n = 0; n < 4; ++n) {
    bf16x4 pk;
#pragma unroll
    for (int j = 0; j < 4; ++j) pk[j] = (bf16_t)(o[n][j] * inv);
    *reinterpret_cast<bf16x4*>(ob + n * 16 + 4 * lg) = pk;
  }
}

// ---------------- launcher ----------------
extern "C" void kernel_launch(void* const* d_in, const int* in_sizes, int n_in,
                              void* d_out, int out_size, void* d_ws, size_t ws_size,
                              hipStream_t stream) {
  (void)in_sizes; (void)n_in; (void)out_size; (void)ws_size;
  const float* q  = (const float*)d_in[0];
  const float* k  = (const float*)d_in[1];
  const float* v  = (const float*)d_in[2];
  const float* Wq = (const float*)d_in[5];
  const float* Wk = (const float*)d_in[6];
  const float* Wv = (const float*)d_in[7];
  const float* Wo = (const float*)d_in[8];
  const float* bo = (const float*)d_in[9];
  float* out = (float*)d_out;

  bf16_t* ws = (bf16_t*)d_ws;
  const size_t SZ_IN = (size_t)MROWS * DIM;  // 4M elems
  const size_t SZ_W  = (size_t)DIM * DIM;    // 1M elems
  bf16_t* qb  = ws;
  bf16_t* kb  = qb  + SZ_IN;
  bf16_t* vb  = kb  + SZ_IN;
  bf16_t* wqb = vb  + SZ_IN;
  bf16_t* wkb = wqb + SZ_W;
  bf16_t* wvb = wkb + SZ_W;
  bf16_t* wob = wvb + SZ_W;
  bf16_t* Qp  = wob + SZ_W;
  bf16_t* Kp  = Qp  + SZ_IN;
  bf16_t* Vtp = Kp  + SZ_IN;
  bf16_t* Xa  = qb;  // alias: qb dead after QKV projection (stream-ordered)

  cvt_all<<<dim3(1024, 16), 256, 0, stream>>>(q, k, v, Wq, Wk, Wv, Wo,
                                              qb, kb, vb, wqb, wkb, wvb, wob);

  gemm_qkv<<<dim3(24, MROWS / 128), 256, 0, stream>>>(qb, kb, vb, wqb, wkb, wvb,
                                                      Qp, Kp, Vtp);

  attn_fused<<<dim3(NQ / 64, HEADS, NB), 256, 0, stream>>>(Qp, Kp, Vtp, Xa);

  gemm_out<<<dim3(DIM / 128, MROWS / 128), 256, 0, stream>>>(Xa, wob, out, bo);
}